// Round 3
// baseline (483.576 us; speedup 1.0000x reference)
//
#include <hip/hip_runtime.h>
#include <stdint.h>

typedef unsigned short u16;
typedef __attribute__((ext_vector_type(8))) short short8;
typedef __attribute__((ext_vector_type(4))) float floatx4;

#define MFMA(a, b, c) __builtin_amdgcn_mfma_f32_16x16x32_bf16((a), (b), (c), 0, 0, 0)

__device__ __forceinline__ u16 f2bf(float f) {
    union { float f; uint32_t u; } x; x.f = f;
    uint32_t u = x.u;
    u += 0x7fffu + ((u >> 16) & 1u);
    return (u16)(u >> 16);
}
__device__ __forceinline__ float bf2f(u16 h) {
    union { uint32_t u; float f; } x; x.u = ((uint32_t)h) << 16;
    return x.f;
}

// ---------------------------------------------------------------------------
// Probe: (a) MFMA C/D orientation (mode 0 = m89 mapping, 1 = transposed,
// 2 = neither -> skip, out stays 0 as a diagnostic). (b) dtype sniff:
// fp32 read as u16 shows huge-exponent bf16 bit patterns; bf16 N(0,1) none.
// ---------------------------------------------------------------------------
__global__ __launch_bounds__(64) void probe_kernel(const u16* __restrict__ x,
                                                   int* __restrict__ flags)
{
    const int lane = threadIdx.x;
    const int lrow = lane & 15, lquad = lane >> 4;
    short8 a, b;
#pragma unroll
    for (int j = 0; j < 8; j++) { a[j] = 0; b[j] = 0; }
    if (lquad == 0) {
        a[0] = (short)f2bf((float)(lrow + 1));
        b[0] = (short)f2bf(1.0f);
    }
    floatx4 c = {0.f, 0.f, 0.f, 0.f};
    c = MFMA(a, b, c);
    bool p0 = true, p1 = true;
#pragma unroll
    for (int i = 0; i < 4; i++) {
        p0 = p0 && (c[i] == (float)(lquad * 4 + i + 1));
        p1 = p1 && (c[i] == (float)(lrow + 1));
    }
    unsigned long long b0 = __ballot(p0 ? 1 : 0);
    unsigned long long b1 = __ballot(p1 ? 1 : 0);
    int cnt = 0;
    for (int t = lane; t < 4096; t += 64) {
        int e = (x[t] >> 7) & 0xFF;
        cnt += (e >= 0xC8) ? 1 : 0;
    }
#pragma unroll
    for (int off = 1; off < 64; off <<= 1) cnt += __shfl_xor(cnt, off);
    if (lane == 0) {
        flags[0] = (b0 == ~0ull) ? 0 : ((b1 == ~0ull) ? 1 : 2);
        flags[1] = (cnt > 8) ? 1 : 0;
    }
}

// ---------------------------------------------------------------------------
// Convert x -> bf16 workspace copy (dt-gated). 8 elems/thread.
// ---------------------------------------------------------------------------
__global__ __launch_bounds__(256) void convert_x_kernel(
    const void* __restrict__ Xv, u16* __restrict__ Xbf,
    const int* __restrict__ flags)
{
    const int dt = flags[1];
    const size_t base = ((size_t)blockIdx.x * 256 + threadIdx.x) * 8;
    if (dt == 0) {
        *(short8*)&Xbf[base] = *(const short8*)((const u16*)Xv + base);
    } else {
        const float* xf = (const float*)Xv + base;
        short8 v;
#pragma unroll
        for (int j = 0; j < 8; j++) v[j] = (short)f2bf(xf[j]);
        *(short8*)&Xbf[base] = v;
    }
}

// ---------------------------------------------------------------------------
// Transpose weights [k][n] -> [n][k] (bf16 out), dtype-gated reads.
// ---------------------------------------------------------------------------
__global__ __launch_bounds__(256) void transpose_w_kernel(
    const void* __restrict__ W0, const void* __restrict__ W1,
    const void* __restrict__ W2, const void* __restrict__ W3,
    u16* __restrict__ WT, const int* __restrict__ flags)
{
    __shared__ u16 tile[32][33];
    const int dt = flags[1];
    const int z = blockIdx.z;
    const void* Wv = (z == 0) ? W0 : (z == 1) ? W1 : (z == 2) ? W2 : W3;
    u16* dst = WT + (size_t)z * 1024 * 1024;
    const int tx = threadIdx.x, ty = threadIdx.y;
    const int n0 = blockIdx.x * 32, k0 = blockIdx.y * 32;
    if (dt == 0) {
        const u16* W = (const u16*)Wv;
#pragma unroll
        for (int i = 0; i < 4; i++)
            tile[ty + i * 8][tx] = W[(size_t)(k0 + ty + i * 8) * 1024 + n0 + tx];
    } else {
        const float* W = (const float*)Wv;
#pragma unroll
        for (int i = 0; i < 4; i++)
            tile[ty + i * 8][tx] = f2bf(W[(size_t)(k0 + ty + i * 8) * 1024 + n0 + tx]);
    }
    __syncthreads();
#pragma unroll
    for (int i = 0; i < 4; i++)
        dst[(size_t)(n0 + ty + i * 8) * 1024 + k0 + tx] = tile[tx][ty + i * 8];
}

// ---------------------------------------------------------------------------
// QKV GEMM: Xbf[4096x1024] @ W -> Q,K [bh][2048][64], V^T [bh][64][2048].
// ---------------------------------------------------------------------------
__global__ __launch_bounds__(256) void gemm_qkv_kernel(
    const u16* __restrict__ X, const u16* __restrict__ WT,
    u16* __restrict__ Q, u16* __restrict__ Kout, u16* __restrict__ VT,
    const int* __restrict__ flags)
{
    const int mode = flags[0];
    if (mode > 1) return;
    __shared__ __align__(16) u16 As[64][40];
    __shared__ __align__(16) u16 Bs[64][40];
    const int mat = blockIdx.z;
    const u16* BW = WT + (size_t)mat * 1024 * 1024;
    const int m0 = blockIdx.y * 64, n0 = blockIdx.x * 64;
    const int tid = threadIdx.x;
    const int wave = tid >> 6, lane = tid & 63;
    const int lrow = lane & 15, lquad = lane >> 4;
    const int srow = tid >> 2, schunk = (tid & 3) * 8;

    floatx4 acc[4];
#pragma unroll
    for (int i = 0; i < 4; i++) acc[i] = (floatx4){0.f, 0.f, 0.f, 0.f};

    for (int k0 = 0; k0 < 1024; k0 += 32) {
        *(short8*)&As[srow][schunk] = *(const short8*)&X[(size_t)(m0 + srow) * 1024 + k0 + schunk];
        *(short8*)&Bs[srow][schunk] = *(const short8*)&BW[(size_t)(n0 + srow) * 1024 + k0 + schunk];
        __syncthreads();
        short8 a = *(const short8*)&As[wave * 16 + lrow][lquad * 8];
#pragma unroll
        for (int nt = 0; nt < 4; nt++) {
            short8 b = *(const short8*)&Bs[nt * 16 + lrow][lquad * 8];
            acc[nt] = MFMA(a, b, acc[nt]);
        }
        __syncthreads();
    }

#pragma unroll
    for (int nt = 0; nt < 4; nt++)
#pragma unroll
        for (int i = 0; i < 4; i++) {
            int gm, gn;
            if (mode == 0) { gm = m0 + wave * 16 + lquad * 4 + i; gn = n0 + nt * 16 + lrow; }
            else           { gm = m0 + wave * 16 + lrow;          gn = n0 + nt * 16 + lquad * 4 + i; }
            const int h = gn >> 6, hd = gn & 63;
            const int b = gm >> 11, s = gm & 2047;
            const int bh = b * 16 + h;
            const u16 val = f2bf(acc[nt][i]);
            if (mat == 0)      Q[((size_t)bh * 2048 + s) * 64 + hd] = val;
            else if (mat == 1) Kout[((size_t)bh * 2048 + s) * 64 + hd] = val;
            else               VT[((size_t)bh * 64 + hd) * 2048 + s] = val;
        }
}

// ---------------------------------------------------------------------------
// Flash attention (causal), dual orientation.
// ---------------------------------------------------------------------------
__global__ __launch_bounds__(256) void attn_kernel(
    const u16* __restrict__ Q, const u16* __restrict__ Kk,
    const u16* __restrict__ VT, u16* __restrict__ ctx,
    const int* __restrict__ flags)
{
    const int mode = flags[0];
    if (mode > 1) return;
    __shared__ __align__(16) u16 P[4][16][72];
    const int qt = blockIdx.x, bh = blockIdx.y;
    const int tid = threadIdx.x, wave = tid >> 6, lane = tid & 63;
    const int lrow = lane & 15, lquad = lane >> 4;
    const float scale = 0.125f;
    const float NEGINF = -__builtin_inff();

    const u16* Qb = Q  + (size_t)bh * 2048 * 64;
    const u16* Kb = Kk + (size_t)bh * 2048 * 64;
    const u16* Vb = VT + (size_t)bh * 64 * 2048;
    const int b_ = bh >> 4, h_ = bh & 15;

    const int qrow0 = qt * 64 + wave * 16;
    const short8 qf0 = *(const short8*)&Qb[(size_t)(qrow0 + lrow) * 64 + lquad * 8];
    const short8 qf1 = *(const short8*)&Qb[(size_t)(qrow0 + lrow) * 64 + 32 + lquad * 8];

    if (mode == 0) {
        float m_i[4], l_i[4];
        floatx4 o[4];
#pragma unroll
        for (int i = 0; i < 4; i++) { m_i[i] = NEGINF; l_i[i] = 0.f; o[i] = (floatx4){0.f, 0.f, 0.f, 0.f}; }
        for (int kt = 0; kt <= qt; kt++) {
            floatx4 s[4];
#pragma unroll
            for (int nt = 0; nt < 4; nt++) {
                const u16* kp = &Kb[(size_t)(kt * 64 + nt * 16 + lrow) * 64 + lquad * 8];
                floatx4 a = (floatx4){0.f, 0.f, 0.f, 0.f};
                a = MFMA(qf0, *(const short8*)kp, a);
                a = MFMA(qf1, *(const short8*)(kp + 32), a);
                s[nt] = a;
            }
            const bool diag = (kt == qt);
            float mx[4] = {NEGINF, NEGINF, NEGINF, NEGINF};
#pragma unroll
            for (int nt = 0; nt < 4; nt++)
#pragma unroll
                for (int i = 0; i < 4; i++) {
                    float v = s[nt][i] * scale;
                    if (diag && (nt * 16 + lrow > wave * 16 + lquad * 4 + i)) v = NEGINF;
                    s[nt][i] = v;
                    mx[i] = fmaxf(mx[i], v);
                }
#pragma unroll
            for (int off = 1; off < 16; off <<= 1)
#pragma unroll
                for (int i = 0; i < 4; i++)
                    mx[i] = fmaxf(mx[i], __shfl_xor(mx[i], off));
            float alpha[4], sum[4];
#pragma unroll
            for (int i = 0; i < 4; i++) {
                const float mnew = fmaxf(m_i[i], mx[i]);
                alpha[i] = (m_i[i] == NEGINF) ? 0.f : __expf(m_i[i] - mnew);
                m_i[i] = mnew;
                sum[i] = 0.f;
            }
#pragma unroll
            for (int nt = 0; nt < 4; nt++)
#pragma unroll
                for (int i = 0; i < 4; i++) {
                    const float v = s[nt][i];
                    const float p = (v == NEGINF) ? 0.f : __expf(v - m_i[i]);
                    s[nt][i] = p;
                    sum[i] += p;
                }
#pragma unroll
            for (int off = 1; off < 16; off <<= 1)
#pragma unroll
                for (int i = 0; i < 4; i++)
                    sum[i] += __shfl_xor(sum[i], off);
#pragma unroll
            for (int i = 0; i < 4; i++) l_i[i] = l_i[i] * alpha[i] + sum[i];
#pragma unroll
            for (int ht = 0; ht < 4; ht++)
#pragma unroll
                for (int i = 0; i < 4; i++) o[ht][i] *= alpha[i];
            __syncthreads();
#pragma unroll
            for (int nt = 0; nt < 4; nt++)
#pragma unroll
                for (int i = 0; i < 4; i++)
                    P[wave][lquad * 4 + i][nt * 16 + lrow] = f2bf(s[nt][i]);
            __syncthreads();
#pragma unroll
            for (int st = 0; st < 2; st++) {
                const short8 pf = *(const short8*)&P[wave][lrow][st * 32 + lquad * 8];
#pragma unroll
                for (int ht = 0; ht < 4; ht++) {
                    const short8 vf = *(const short8*)&Vb[(size_t)(ht * 16 + lrow) * 2048 + kt * 64 + st * 32 + lquad * 8];
                    o[ht] = MFMA(pf, vf, o[ht]);
                }
            }
        }
#pragma unroll
        for (int ht = 0; ht < 4; ht++)
#pragma unroll
            for (int i = 0; i < 4; i++) {
                const int srow_ = qt * 64 + wave * 16 + lquad * 4 + i;
                const float v = o[ht][i] / l_i[i];
                ctx[((size_t)(b_ * 2048 + srow_)) * 1024 + h_ * 64 + ht * 16 + lrow] = f2bf(v);
            }
    } else {
        float m_s = NEGINF, l_s = 0.f;
        floatx4 o[4];
#pragma unroll
        for (int i = 0; i < 4; i++) o[i] = (floatx4){0.f, 0.f, 0.f, 0.f};
        for (int kt = 0; kt <= qt; kt++) {
            floatx4 s[4];
#pragma unroll
            for (int nt = 0; nt < 4; nt++) {
                const u16* kp = &Kb[(size_t)(kt * 64 + nt * 16 + lrow) * 64 + lquad * 8];
                floatx4 a = (floatx4){0.f, 0.f, 0.f, 0.f};
                a = MFMA(qf0, *(const short8*)kp, a);
                a = MFMA(qf1, *(const short8*)(kp + 32), a);
                s[nt] = a;
            }
            const bool diag = (kt == qt);
            float mx = NEGINF;
#pragma unroll
            for (int nt = 0; nt < 4; nt++)
#pragma unroll
                for (int i = 0; i < 4; i++) {
                    float v = s[nt][i] * scale;
                    if (diag && (nt * 16 + lquad * 4 + i > wave * 16 + lrow)) v = NEGINF;
                    s[nt][i] = v;
                    mx = fmaxf(mx, v);
                }
            mx = fmaxf(mx, __shfl_xor(mx, 16));
            mx = fmaxf(mx, __shfl_xor(mx, 32));
            const float mnew = fmaxf(m_s, mx);
            const float alpha = (m_s == NEGINF) ? 0.f : __expf(m_s - mnew);
            m_s = mnew;
            float sum = 0.f;
#pragma unroll
            for (int nt = 0; nt < 4; nt++)
#pragma unroll
                for (int i = 0; i < 4; i++) {
                    const float v = s[nt][i];
                    const float p = (v == NEGINF) ? 0.f : __expf(v - mnew);
                    s[nt][i] = p;
                    sum += p;
                }
            sum += __shfl_xor(sum, 16);
            sum += __shfl_xor(sum, 32);
            l_s = l_s * alpha + sum;
#pragma unroll
            for (int ht = 0; ht < 4; ht++)
#pragma unroll
                for (int i = 0; i < 4; i++) o[ht][i] *= alpha;
            __syncthreads();
#pragma unroll
            for (int nt = 0; nt < 4; nt++)
#pragma unroll
                for (int i = 0; i < 4; i++)
                    P[wave][lrow][nt * 16 + lquad * 4 + i] = f2bf(s[nt][i]);
            __syncthreads();
#pragma unroll
            for (int st = 0; st < 2; st++) {
                const short8 pf = *(const short8*)&P[wave][lrow][st * 32 + lquad * 8];
#pragma unroll
                for (int ht = 0; ht < 4; ht++) {
                    const short8 vf = *(const short8*)&Vb[(size_t)(ht * 16 + lrow) * 2048 + kt * 64 + st * 32 + lquad * 8];
                    o[ht] = MFMA(pf, vf, o[ht]);
                }
            }
        }
        const int srow_ = qt * 64 + wave * 16 + lrow;
#pragma unroll
        for (int ht = 0; ht < 4; ht++)
#pragma unroll
            for (int i = 0; i < 4; i++) {
                const float v = o[ht][i] / l_s;
                ctx[((size_t)(b_ * 2048 + srow_)) * 1024 + h_ * 64 + ht * 16 + lquad * 4 + i] = f2bf(v);
            }
    }
}

// ---------------------------------------------------------------------------
// Output projection: ctx @ Wo + bo -> out, dt-gated bias read AND store dtype.
// ---------------------------------------------------------------------------
__global__ __launch_bounds__(256) void gemm_out_kernel(
    const u16* __restrict__ X, const u16* __restrict__ WT,
    const void* __restrict__ bias, void* __restrict__ outv,
    const int* __restrict__ flags)
{
    const int mode = flags[0];
    if (mode > 1) return;
    const int dt = flags[1];
    __shared__ __align__(16) u16 As[64][40];
    __shared__ __align__(16) u16 Bs[64][40];
    const int m0 = blockIdx.y * 64, n0 = blockIdx.x * 64;
    const int tid = threadIdx.x;
    const int wave = tid >> 6, lane = tid & 63;
    const int lrow = lane & 15, lquad = lane >> 4;
    const int srow = tid >> 2, schunk = (tid & 3) * 8;

    floatx4 acc[4];
#pragma unroll
    for (int i = 0; i < 4; i++) acc[i] = (floatx4){0.f, 0.f, 0.f, 0.f};

    for (int k0 = 0; k0 < 1024; k0 += 32) {
        *(short8*)&As[srow][schunk] = *(const short8*)&X[(size_t)(m0 + srow) * 1024 + k0 + schunk];
        *(short8*)&Bs[srow][schunk] = *(const short8*)&WT[(size_t)(n0 + srow) * 1024 + k0 + schunk];
        __syncthreads();
        short8 a = *(const short8*)&As[wave * 16 + lrow][lquad * 8];
#pragma unroll
        for (int nt = 0; nt < 4; nt++) {
            short8 b = *(const short8*)&Bs[nt * 16 + lrow][lquad * 8];
            acc[nt] = MFMA(a, b, acc[nt]);
        }
        __syncthreads();
    }

#pragma unroll
    for (int nt = 0; nt < 4; nt++)
#pragma unroll
        for (int i = 0; i < 4; i++) {
            int gm, gn;
            if (mode == 0) { gm = m0 + wave * 16 + lquad * 4 + i; gn = n0 + nt * 16 + lrow; }
            else           { gm = m0 + wave * 16 + lrow;          gn = n0 + nt * 16 + lquad * 4 + i; }
            const float bv = (dt == 0) ? bf2f(((const u16*)bias)[gn]) : ((const float*)bias)[gn];
            const float r = acc[nt][i] + bv;
            if (dt == 0) ((u16*)outv)[(size_t)gm * 1024 + gn] = f2bf(r);
            else         ((float*)outv)[(size_t)gm * 1024 + gn] = r;
        }
}

// ---------------------------------------------------------------------------
extern "C" void kernel_launch(void* const* d_in, const int* in_sizes, int n_in,
                              void* d_out, int out_size, void* d_ws, size_t ws_size,
                              hipStream_t stream) {
    int* flags = (int*)d_ws;
    u16* ws = (u16*)d_ws + 64;

    const size_t MB1 = 1024 * 1024;
    u16* WT   = ws;              // 4 transposed weights (bf16)
    u16* Qw   = ws + 4 * MB1;    // [bh][2048][64]
    u16* Kw   = ws + 8 * MB1;    // [bh][2048][64]
    u16* VTw  = ws + 12 * MB1;   // [bh][64][2048]
    u16* ctxw = ws + 16 * MB1;   // [4096][1024]
    u16* Xbf  = ws + 20 * MB1;   // x as bf16 [4096][1024]

    probe_kernel<<<1, 64, 0, stream>>>((const u16*)d_in[0], flags);
    convert_x_kernel<<<2048, 256, 0, stream>>>(d_in[0], Xbf, flags);
    transpose_w_kernel<<<dim3(32, 32, 4), dim3(32, 8), 0, stream>>>(
        d_in[1], d_in[2], d_in[3], d_in[4], WT, flags);
    gemm_qkv_kernel<<<dim3(16, 64, 3), 256, 0, stream>>>(Xbf, WT, Qw, Kw, VTw, flags);
    attn_kernel<<<dim3(32, 32), 256, 0, stream>>>(Qw, Kw, VTw, ctxw, flags);
    gemm_out_kernel<<<dim3(16, 64), 256, 0, stream>>>(ctxw, WT + 3 * MB1, d_in[5], d_out, flags);
}

// Round 5
// 318.449 us; speedup vs baseline: 1.5185x; 1.5185x over previous
//
#include <hip/hip_runtime.h>
#include <stdint.h>

typedef unsigned short u16;
typedef __attribute__((ext_vector_type(8))) short short8;
typedef __attribute__((ext_vector_type(4))) float floatx4;

#define MFMA(a, b, c) __builtin_amdgcn_mfma_f32_16x16x32_bf16((a), (b), (c), 0, 0, 0)

__device__ __forceinline__ u16 f2bf(float f) {
    union { float f; uint32_t u; } x; x.f = f;
    uint32_t u = x.u;
    u += 0x7fffu + ((u >> 16) & 1u);
    return (u16)(u >> 16);
}
__device__ __forceinline__ float bf2f(u16 h) {
    union { uint32_t u; float f; } x; x.u = ((uint32_t)h) << 16;
    return x.f;
}

// ---------------------------------------------------------------------------
// x (fp32) -> bf16 workspace copy. 8 elems/thread.
// ---------------------------------------------------------------------------
__global__ __launch_bounds__(256) void convert_x_kernel(
    const float* __restrict__ Xv, u16* __restrict__ Xbf)
{
    const size_t base = ((size_t)blockIdx.x * 256 + threadIdx.x) * 8;
    const float* xf = Xv + base;
    short8 v;
#pragma unroll
    for (int j = 0; j < 8; j++) v[j] = (short)f2bf(xf[j]);
    *(short8*)&Xbf[base] = v;
}

// ---------------------------------------------------------------------------
// Transpose weights [k][n] (fp32) -> [n][k] (bf16).
// ---------------------------------------------------------------------------
__global__ __launch_bounds__(256) void transpose_w_kernel(
    const float* __restrict__ W0, const float* __restrict__ W1,
    const float* __restrict__ W2, const float* __restrict__ W3,
    u16* __restrict__ WT)
{
    __shared__ u16 tile[32][33];
    const int z = blockIdx.z;
    const float* W = (z == 0) ? W0 : (z == 1) ? W1 : (z == 2) ? W2 : W3;
    u16* dst = WT + (size_t)z * 1024 * 1024;
    const int tx = threadIdx.x, ty = threadIdx.y;
    const int n0 = blockIdx.x * 32, k0 = blockIdx.y * 32;
#pragma unroll
    for (int i = 0; i < 4; i++)
        tile[ty + i * 8][tx] = f2bf(W[(size_t)(k0 + ty + i * 8) * 1024 + n0 + tx]);
    __syncthreads();
#pragma unroll
    for (int i = 0; i < 4; i++)
        dst[(size_t)(n0 + ty + i * 8) * 1024 + k0 + tx] = tile[tx][ty + i * 8];
}

// ---------------------------------------------------------------------------
// QKV GEMM: Xbf[4096x1024] @ W -> Q,K [bh][2048][64], V^T [bh][64][2048].
// C/D mapping (m89, HW-confirmed r3): row=lquad*4+i, col=lrow.
// ---------------------------------------------------------------------------
__global__ __launch_bounds__(256) void gemm_qkv_kernel(
    const u16* __restrict__ X, const u16* __restrict__ WT,
    u16* __restrict__ Q, u16* __restrict__ Kout, u16* __restrict__ VT)
{
    __shared__ __align__(16) u16 As[64][40];
    __shared__ __align__(16) u16 Bs[64][40];
    const int mat = blockIdx.z;
    const u16* BW = WT + (size_t)mat * 1024 * 1024;
    const int m0 = blockIdx.y * 64, n0 = blockIdx.x * 64;
    const int tid = threadIdx.x;
    const int wave = tid >> 6, lane = tid & 63;
    const int lrow = lane & 15, lquad = lane >> 4;
    const int srow = tid >> 2, schunk = (tid & 3) * 8;

    floatx4 acc[4];
#pragma unroll
    for (int i = 0; i < 4; i++) acc[i] = (floatx4){0.f, 0.f, 0.f, 0.f};

    for (int k0 = 0; k0 < 1024; k0 += 32) {
        *(short8*)&As[srow][schunk] = *(const short8*)&X[(size_t)(m0 + srow) * 1024 + k0 + schunk];
        *(short8*)&Bs[srow][schunk] = *(const short8*)&BW[(size_t)(n0 + srow) * 1024 + k0 + schunk];
        __syncthreads();
        short8 a = *(const short8*)&As[wave * 16 + lrow][lquad * 8];
#pragma unroll
        for (int nt = 0; nt < 4; nt++) {
            short8 b = *(const short8*)&Bs[nt * 16 + lrow][lquad * 8];
            acc[nt] = MFMA(a, b, acc[nt]);
        }
        __syncthreads();
    }

#pragma unroll
    for (int nt = 0; nt < 4; nt++)
#pragma unroll
        for (int i = 0; i < 4; i++) {
            const int gm = m0 + wave * 16 + lquad * 4 + i;
            const int gn = n0 + nt * 16 + lrow;
            const int h = gn >> 6, hd = gn & 63;
            const int b = gm >> 11, s = gm & 2047;
            const int bh = b * 16 + h;
            const u16 val = f2bf(acc[nt][i]);
            if (mat == 0)      Q[((size_t)bh * 2048 + s) * 64 + hd] = val;
            else if (mat == 1) Kout[((size_t)bh * 2048 + s) * 64 + hd] = val;
            else               VT[((size_t)bh * 64 + hd) * 2048 + s] = val;
        }
}

// ---------------------------------------------------------------------------
// Flash attention (causal), barrier-free, one wave per 16-row q-strip.
// S^T = MFMA(K-frag, Q-frag): each lane holds 16 kv-values of ONE q-row
// (q = q0+lrow) -> in-lane softmax reduction + 2 shuffles (xor16, xor32).
// P packed to wave-private LDS (b64 writes), PV: O^T = MFMA(V^T-frag, P-frag).
// Task map: w = blockIdx*4+wave; bh = w&31; strip p = 127-(w>>5)
// (longest strips launch first; all 4096 waves co-resident at 4 waves/SIMD).
// ---------------------------------------------------------------------------
__global__ __launch_bounds__(256, 4) void attn_kernel(
    const u16* __restrict__ Q, const u16* __restrict__ Kk,
    const u16* __restrict__ VT, u16* __restrict__ ctx)
{
    __shared__ __align__(16) u16 P[4][16][72];  // per-wave 16 q x 64 kv (+pad)
    const int tid = threadIdx.x, wave = tid >> 6, lane = tid & 63;
    const int lrow = lane & 15, lquad = lane >> 4;
    const float scale = 0.125f;  // 1/sqrt(64)
    const float NEGINF = -__builtin_inff();

    const int w = blockIdx.x * 4 + wave;
    const int bh = w & 31;
    const int p = 127 - (w >> 5);
    const int q0 = p * 16;
    const int ntiles = (p >> 2) + 1;

    const u16* Qb = Q  + (size_t)bh * 2048 * 64;
    const u16* Kb = Kk + (size_t)bh * 2048 * 64;
    const u16* Vb = VT + (size_t)bh * 64 * 2048;

    // Q as B-operand: lane(n=lrow) supplies Q[q0+lrow][k=lquad*8+j], halves k<32, k>=32
    const short8 qf0 = *(const short8*)&Qb[(size_t)(q0 + lrow) * 64 + lquad * 8];
    const short8 qf1 = *(const short8*)&Qb[(size_t)(q0 + lrow) * 64 + 32 + lquad * 8];

    const int myq = q0 + lrow;
    float m_s = NEGINF, l_s = 0.f;
    floatx4 o[4];
#pragma unroll
    for (int i = 0; i < 4; i++) o[i] = (floatx4){0.f, 0.f, 0.f, 0.f};

    for (int kt = 0; kt < ntiles; kt++) {
        // K as A-operand: lane(m=lrow) supplies K[kt*64+nt*16+lrow][k]
        short8 kf0[4], kf1[4];
#pragma unroll
        for (int nt = 0; nt < 4; nt++) {
            const u16* kp = &Kb[(size_t)(kt * 64 + nt * 16 + lrow) * 64 + lquad * 8];
            kf0[nt] = *(const short8*)kp;
            kf1[nt] = *(const short8*)(kp + 32);
        }
        // V^T as A-operand (issued early; consumed after softmax)
        short8 vf[2][4];
#pragma unroll
        for (int st = 0; st < 2; st++)
#pragma unroll
            for (int ht = 0; ht < 4; ht++)
                vf[st][ht] = *(const short8*)&Vb[(size_t)(ht * 16 + lrow) * 2048 + kt * 64 + st * 32 + lquad * 8];

        // S^T[kv = nt*16+lquad*4+i][q = lrow]
        floatx4 s[4];
#pragma unroll
        for (int nt = 0; nt < 4; nt++) {
            floatx4 a = (floatx4){0.f, 0.f, 0.f, 0.f};
            a = MFMA(kf0[nt], qf0, a);
            a = MFMA(kf1[nt], qf1, a);
            s[nt] = a;
        }

        const bool diag = (kt == ntiles - 1);
        float mx = NEGINF;
#pragma unroll
        for (int nt = 0; nt < 4; nt++)
#pragma unroll
            for (int i = 0; i < 4; i++) {
                float v = s[nt][i] * scale;
                if (diag && (kt * 64 + nt * 16 + lquad * 4 + i > myq)) v = NEGINF;
                s[nt][i] = v;
                mx = fmaxf(mx, v);
            }
        mx = fmaxf(mx, __shfl_xor(mx, 16));
        mx = fmaxf(mx, __shfl_xor(mx, 32));
        const float mnew = fmaxf(m_s, mx);            // always finite
        const float alpha = __expf(m_s - mnew);       // first iter: exp(-inf)=0
        m_s = mnew;
        float sum = 0.f;
#pragma unroll
        for (int nt = 0; nt < 4; nt++)
#pragma unroll
            for (int i = 0; i < 4; i++) {
                const float pv = __expf(s[nt][i] - mnew);  // masked -> exp(-inf)=0
                s[nt][i] = pv;
                sum += pv;
            }
        sum += __shfl_xor(sum, 16);
        sum += __shfl_xor(sum, 32);
        l_s = l_s * alpha + sum;
#pragma unroll
        for (int ht = 0; ht < 4; ht++)
#pragma unroll
            for (int i = 0; i < 4; i++) o[ht][i] *= alpha;

        // P -> wave-private LDS, layout Pl[q][kv]; 4 consecutive kv pack into b64.
#pragma unroll
        for (int nt = 0; nt < 4; nt++) {
            uint32_t pk0 = (uint32_t)f2bf(s[nt][0]) | ((uint32_t)f2bf(s[nt][1]) << 16);
            uint32_t pk1 = (uint32_t)f2bf(s[nt][2]) | ((uint32_t)f2bf(s[nt][3]) << 16);
            uint2 pk = {pk0, pk1};
            *(uint2*)&P[wave][lrow][nt * 16 + lquad * 4] = pk;
        }
        // O^T[hd][q] += V^T[hd][kv] P[kv][q]; P as B-operand from LDS.
#pragma unroll
        for (int st = 0; st < 2; st++) {
            const short8 pf = *(const short8*)&P[wave][lrow][st * 32 + lquad * 8];
#pragma unroll
            for (int ht = 0; ht < 4; ht++)
                o[ht] = MFMA(vf[st][ht], pf, o[ht]);
        }
    }

    // O^T C-layout: lane holds O[q=q0+lrow][hd=ht*16+lquad*4+i]; pack 4 hd -> 8B.
    const int b_ = bh >> 4, h_ = bh & 15;
    const float inv_l = 1.0f / l_s;
#pragma unroll
    for (int ht = 0; ht < 4; ht++) {
        uint32_t pk0 = (uint32_t)f2bf(o[ht][0] * inv_l) | ((uint32_t)f2bf(o[ht][1] * inv_l) << 16);
        uint32_t pk1 = (uint32_t)f2bf(o[ht][2] * inv_l) | ((uint32_t)f2bf(o[ht][3] * inv_l) << 16);
        uint2 pk = {pk0, pk1};
        *(uint2*)&ctx[((size_t)(b_ * 2048 + q0 + lrow)) * 1024 + h_ * 64 + ht * 16 + lquad * 4] = pk;
    }
}

// ---------------------------------------------------------------------------
// Output projection: ctx @ Wo + bo -> out (fp32 store, fp32 bias).
// ---------------------------------------------------------------------------
__global__ __launch_bounds__(256) void gemm_out_kernel(
    const u16* __restrict__ X, const u16* __restrict__ WT,
    const float* __restrict__ bias, float* __restrict__ out)
{
    __shared__ __align__(16) u16 As[64][40];
    __shared__ __align__(16) u16 Bs[64][40];
    const int m0 = blockIdx.y * 64, n0 = blockIdx.x * 64;
    const int tid = threadIdx.x;
    const int wave = tid >> 6, lane = tid & 63;
    const int lrow = lane & 15, lquad = lane >> 4;
    const int srow = tid >> 2, schunk = (tid & 3) * 8;

    floatx4 acc[4];
#pragma unroll
    for (int i = 0; i < 4; i++) acc[i] = (floatx4){0.f, 0.f, 0.f, 0.f};

    for (int k0 = 0; k0 < 1024; k0 += 32) {
        *(short8*)&As[srow][schunk] = *(const short8*)&X[(size_t)(m0 + srow) * 1024 + k0 + schunk];
        *(short8*)&Bs[srow][schunk] = *(const short8*)&WT[(size_t)(n0 + srow) * 1024 + k0 + schunk];
        __syncthreads();
        short8 a = *(const short8*)&As[wave * 16 + lrow][lquad * 8];
#pragma unroll
        for (int nt = 0; nt < 4; nt++) {
            short8 b = *(const short8*)&Bs[nt * 16 + lrow][lquad * 8];
            acc[nt] = MFMA(a, b, acc[nt]);
        }
        __syncthreads();
    }

#pragma unroll
    for (int nt = 0; nt < 4; nt++)
#pragma unroll
        for (int i = 0; i < 4; i++) {
            const int gm = m0 + wave * 16 + lquad * 4 + i;
            const int gn = n0 + nt * 16 + lrow;
            out[(size_t)gm * 1024 + gn] = acc[nt][i] + bias[gn];
        }
}

// ---------------------------------------------------------------------------
extern "C" void kernel_launch(void* const* d_in, const int* in_sizes, int n_in,
                              void* d_out, int out_size, void* d_ws, size_t ws_size,
                              hipStream_t stream) {
    u16* ws = (u16*)d_ws + 64;

    const size_t MB1 = 1024 * 1024;
    u16* WT   = ws;              // 4 transposed weights (bf16)
    u16* Qw   = ws + 4 * MB1;    // [bh][2048][64]
    u16* Kw   = ws + 8 * MB1;    // [bh][2048][64]
    u16* VTw  = ws + 12 * MB1;   // [bh][64][2048]
    u16* ctxw = ws + 16 * MB1;   // [4096][1024]
    u16* Xbf  = ws + 20 * MB1;   // x as bf16 [4096][1024]

    convert_x_kernel<<<2048, 256, 0, stream>>>((const float*)d_in[0], Xbf);
    transpose_w_kernel<<<dim3(32, 32, 4), dim3(32, 8), 0, stream>>>(
        (const float*)d_in[1], (const float*)d_in[2], (const float*)d_in[3],
        (const float*)d_in[4], WT);
    gemm_qkv_kernel<<<dim3(16, 64, 3), 256, 0, stream>>>(Xbf, WT, Qw, Kw, VTw);
    attn_kernel<<<1024, 256, 0, stream>>>(Qw, Kw, VTw, ctxw);
    gemm_out_kernel<<<dim3(16, 64), 256, 0, stream>>>(ctxw, WT + 3 * MB1, (const float*)d_in[5], (float*)d_out);
}

// Round 6
// 216.152 us; speedup vs baseline: 2.2372x; 1.4733x over previous
//
#include <hip/hip_runtime.h>
#include <stdint.h>

typedef unsigned short u16;
typedef __attribute__((ext_vector_type(8))) short short8;
typedef __attribute__((ext_vector_type(4))) float floatx4;

#define MFMA(a, b, c) __builtin_amdgcn_mfma_f32_16x16x32_bf16((a), (b), (c), 0, 0, 0)

__device__ __forceinline__ u16 f2bf(float f) {
    union { float f; uint32_t u; } x; x.f = f;
    uint32_t u = x.u;
    u += 0x7fffu + ((u >> 16) & 1u);
    return (u16)(u >> 16);
}

// ---------------------------------------------------------------------------
// x (fp32) -> bf16 workspace copy. 8 elems/thread.
// ---------------------------------------------------------------------------
__global__ __launch_bounds__(256) void convert_x_kernel(
    const float* __restrict__ Xv, u16* __restrict__ Xbf)
{
    const size_t base = ((size_t)blockIdx.x * 256 + threadIdx.x) * 8;
    const float* xf = Xv + base;
    short8 v;
#pragma unroll
    for (int j = 0; j < 8; j++) v[j] = (short)f2bf(xf[j]);
    *(short8*)&Xbf[base] = v;
}

// ---------------------------------------------------------------------------
// Transpose weights [k][n] (fp32) -> [n][k] (bf16).
// ---------------------------------------------------------------------------
__global__ __launch_bounds__(256) void transpose_w_kernel(
    const float* __restrict__ W0, const float* __restrict__ W1,
    const float* __restrict__ W2, const float* __restrict__ W3,
    u16* __restrict__ WT)
{
    __shared__ u16 tile[32][33];
    const int z = blockIdx.z;
    const float* W = (z == 0) ? W0 : (z == 1) ? W1 : (z == 2) ? W2 : W3;
    u16* dst = WT + (size_t)z * 1024 * 1024;
    const int tx = threadIdx.x, ty = threadIdx.y;
    const int n0 = blockIdx.x * 32, k0 = blockIdx.y * 32;
#pragma unroll
    for (int i = 0; i < 4; i++)
        tile[ty + i * 8][tx] = f2bf(W[(size_t)(k0 + ty + i * 8) * 1024 + n0 + tx]);
    __syncthreads();
#pragma unroll
    for (int i = 0; i < 4; i++)
        dst[(size_t)(n0 + ty + i * 8) * 1024 + k0 + tx] = tile[tx][ty + i * 8];
}

// ---------------------------------------------------------------------------
// QKV GEMM: Xbf[4096x1024] @ W -> Q,K [bh][2048][64], V^T [bh][64][2048].
// C/D mapping (m89, HW-confirmed r3): row=lquad*4+i, col=lrow.
// ---------------------------------------------------------------------------
__global__ __launch_bounds__(256) void gemm_qkv_kernel(
    const u16* __restrict__ X, const u16* __restrict__ WT,
    u16* __restrict__ Q, u16* __restrict__ Kout, u16* __restrict__ VT)
{
    __shared__ __align__(16) u16 As[64][40];
    __shared__ __align__(16) u16 Bs[64][40];
    const int mat = blockIdx.z;
    const u16* BW = WT + (size_t)mat * 1024 * 1024;
    const int m0 = blockIdx.y * 64, n0 = blockIdx.x * 64;
    const int tid = threadIdx.x;
    const int wave = tid >> 6, lane = tid & 63;
    const int lrow = lane & 15, lquad = lane >> 4;
    const int srow = tid >> 2, schunk = (tid & 3) * 8;

    floatx4 acc[4];
#pragma unroll
    for (int i = 0; i < 4; i++) acc[i] = (floatx4){0.f, 0.f, 0.f, 0.f};

    for (int k0 = 0; k0 < 1024; k0 += 32) {
        *(short8*)&As[srow][schunk] = *(const short8*)&X[(size_t)(m0 + srow) * 1024 + k0 + schunk];
        *(short8*)&Bs[srow][schunk] = *(const short8*)&BW[(size_t)(n0 + srow) * 1024 + k0 + schunk];
        __syncthreads();
        short8 a = *(const short8*)&As[wave * 16 + lrow][lquad * 8];
#pragma unroll
        for (int nt = 0; nt < 4; nt++) {
            short8 b = *(const short8*)&Bs[nt * 16 + lrow][lquad * 8];
            acc[nt] = MFMA(a, b, acc[nt]);
        }
        __syncthreads();
    }

#pragma unroll
    for (int nt = 0; nt < 4; nt++)
#pragma unroll
        for (int i = 0; i < 4; i++) {
            const int gm = m0 + wave * 16 + lquad * 4 + i;
            const int gn = n0 + nt * 16 + lrow;
            const int h = gn >> 6, hd = gn & 63;
            const int b = gm >> 11, s = gm & 2047;
            const int bh = b * 16 + h;
            const u16 val = f2bf(acc[nt][i]);
            if (mat == 0)      Q[((size_t)bh * 2048 + s) * 64 + hd] = val;
            else if (mat == 1) Kout[((size_t)bh * 2048 + s) * 64 + hd] = val;
            else               VT[((size_t)bh * 64 + hd) * 2048 + s] = val;
        }
}

// ---------------------------------------------------------------------------
// Flash attention (causal), LDS-shared K/V tiles.
// Block = 4 waves x one (bh, 64-row q-block). Per kv-tile: 256 threads stage
// K-tile [64][64] + V^T-tile [64][64] into padded LDS (register-prefetched),
// then each wave runs the r5 S^T/softmax/PV pipeline on its 16 q-rows,
// reading K/V fragments from LDS (4x less VMEM traffic per wave-iter).
// All 4 waves share the same diagonal (= last) tile -> uniform barrier count.
// Balance: qb(g) = g<16 ? 31-g : g-16 makes each CU's 4 blocks sum to 62
// tiles, longest-first.
// ---------------------------------------------------------------------------
__global__ __launch_bounds__(256, 4) void attn_kernel(
    const u16* __restrict__ Q, const u16* __restrict__ Kk,
    const u16* __restrict__ VT, u16* __restrict__ ctx)
{
    __shared__ __align__(16) u16 Ks[64][72];
    __shared__ __align__(16) u16 Vs[64][72];
    __shared__ __align__(16) u16 P[4][16][72];
    const int tid = threadIdx.x, wave = tid >> 6, lane = tid & 63;
    const int lrow = lane & 15, lquad = lane >> 4;
    const float scale = 0.125f;  // 1/sqrt(64)
    const float NEGINF = -__builtin_inff();

    const int bh = blockIdx.x & 31;
    const int g = blockIdx.x >> 5;
    const int qb = (g < 16) ? (31 - g) : (g - 16);
    const int ntiles = qb + 1;
    const int q0 = qb * 64 + wave * 16;

    const u16* Qb = Q  + (size_t)bh * 2048 * 64;
    const u16* Kb = Kk + (size_t)bh * 2048 * 64;
    const u16* Vb = VT + (size_t)bh * 64 * 2048;

    // Q as B-operand: lane(n=lrow) supplies Q[q0+lrow][k=lquad*8+j]
    const short8 qf0 = *(const short8*)&Qb[(size_t)(q0 + lrow) * 64 + lquad * 8];
    const short8 qf1 = *(const short8*)&Qb[(size_t)(q0 + lrow) * 64 + 32 + lquad * 8];

    const int myq = q0 + lrow;
    float m_s = NEGINF, l_s = 0.f;
    floatx4 o[4];
#pragma unroll
    for (int i = 0; i < 4; i++) o[i] = (floatx4){0.f, 0.f, 0.f, 0.f};

    // staging coords: thread covers 2 chunks of each tile (idx, idx+256)
    const int r0 = tid >> 3, c0 = (tid & 7) * 8;          // j=0
    const int r1 = (tid + 256) >> 3, c1 = c0;             // j=1 (rows 32..63)

    // prefetch tile 0 into registers
    short8 kreg0 = *(const short8*)&Kb[(size_t)r0 * 64 + c0];
    short8 kreg1 = *(const short8*)&Kb[(size_t)r1 * 64 + c1];
    short8 vreg0 = *(const short8*)&Vb[(size_t)r0 * 2048 + c0];
    short8 vreg1 = *(const short8*)&Vb[(size_t)r1 * 2048 + c1];

    for (int kt = 0; kt < ntiles; kt++) {
        __syncthreads();  // previous tile's compute done; LDS safe to overwrite
        *(short8*)&Ks[r0][c0] = kreg0;
        *(short8*)&Ks[r1][c1] = kreg1;
        *(short8*)&Vs[r0][c0] = vreg0;
        *(short8*)&Vs[r1][c1] = vreg1;
        if (kt + 1 < ntiles) {  // prefetch next tile; flies during compute
            kreg0 = *(const short8*)&Kb[(size_t)((kt + 1) * 64 + r0) * 64 + c0];
            kreg1 = *(const short8*)&Kb[(size_t)((kt + 1) * 64 + r1) * 64 + c1];
            vreg0 = *(const short8*)&Vb[(size_t)r0 * 2048 + (kt + 1) * 64 + c0];
            vreg1 = *(const short8*)&Vb[(size_t)r1 * 2048 + (kt + 1) * 64 + c1];
        }
        __syncthreads();  // staged tile visible

        // S^T[kv = nt*16+lquad*4+i][q = lrow] from LDS K, register Q
        floatx4 s[4];
#pragma unroll
        for (int nt = 0; nt < 4; nt++) {
            const short8 kf0 = *(const short8*)&Ks[nt * 16 + lrow][lquad * 8];
            const short8 kf1 = *(const short8*)&Ks[nt * 16 + lrow][32 + lquad * 8];
            floatx4 a = (floatx4){0.f, 0.f, 0.f, 0.f};
            a = MFMA(kf0, qf0, a);
            a = MFMA(kf1, qf1, a);
            s[nt] = a;
        }

        const bool diag = (kt == ntiles - 1);
        float mx = NEGINF;
#pragma unroll
        for (int nt = 0; nt < 4; nt++)
#pragma unroll
            for (int i = 0; i < 4; i++) {
                float v = s[nt][i] * scale;
                if (diag && (kt * 64 + nt * 16 + lquad * 4 + i > myq)) v = NEGINF;
                s[nt][i] = v;
                mx = fmaxf(mx, v);
            }
        mx = fmaxf(mx, __shfl_xor(mx, 16));
        mx = fmaxf(mx, __shfl_xor(mx, 32));
        const float mnew = fmaxf(m_s, mx);            // always finite
        const float alpha = __expf(m_s - mnew);       // first iter: exp(-inf)=0
        m_s = mnew;
        float sum = 0.f;
#pragma unroll
        for (int nt = 0; nt < 4; nt++)
#pragma unroll
            for (int i = 0; i < 4; i++) {
                const float pv = __expf(s[nt][i] - mnew);  // masked -> 0
                s[nt][i] = pv;
                sum += pv;
            }
        sum += __shfl_xor(sum, 16);
        sum += __shfl_xor(sum, 32);
        l_s = l_s * alpha + sum;
#pragma unroll
        for (int ht = 0; ht < 4; ht++)
#pragma unroll
            for (int i = 0; i < 4; i++) o[ht][i] *= alpha;

        // P -> wave-private LDS, layout P[q][kv]; 4 consecutive kv pack to b64
#pragma unroll
        for (int nt = 0; nt < 4; nt++) {
            uint32_t pk0 = (uint32_t)f2bf(s[nt][0]) | ((uint32_t)f2bf(s[nt][1]) << 16);
            uint32_t pk1 = (uint32_t)f2bf(s[nt][2]) | ((uint32_t)f2bf(s[nt][3]) << 16);
            uint2 pk = {pk0, pk1};
            *(uint2*)&P[wave][lrow][nt * 16 + lquad * 4] = pk;
        }
        // O^T[hd][q] += V^T[hd][kv] P[kv][q]; V from LDS, P as B-operand
#pragma unroll
        for (int st = 0; st < 2; st++) {
            const short8 pf = *(const short8*)&P[wave][lrow][st * 32 + lquad * 8];
#pragma unroll
            for (int ht = 0; ht < 4; ht++) {
                const short8 vf = *(const short8*)&Vs[ht * 16 + lrow][st * 32 + lquad * 8];
                o[ht] = MFMA(vf, pf, o[ht]);
            }
        }
    }

    // O^T C-layout: lane holds O[q=q0+lrow][hd=ht*16+lquad*4+i]; pack 4 hd -> 8B
    const int b_ = bh >> 4, h_ = bh & 15;
    const float inv_l = 1.0f / l_s;
#pragma unroll
    for (int ht = 0; ht < 4; ht++) {
        uint32_t pk0 = (uint32_t)f2bf(o[ht][0] * inv_l) | ((uint32_t)f2bf(o[ht][1] * inv_l) << 16);
        uint32_t pk1 = (uint32_t)f2bf(o[ht][2] * inv_l) | ((uint32_t)f2bf(o[ht][3] * inv_l) << 16);
        uint2 pk = {pk0, pk1};
        *(uint2*)&ctx[((size_t)(b_ * 2048 + q0 + lrow)) * 1024 + h_ * 64 + ht * 16 + lquad * 4] = pk;
    }
}

// ---------------------------------------------------------------------------
// Output projection: ctx @ Wo + bo -> out (fp32 store, fp32 bias).
// ---------------------------------------------------------------------------
__global__ __launch_bounds__(256) void gemm_out_kernel(
    const u16* __restrict__ X, const u16* __restrict__ WT,
    const float* __restrict__ bias, float* __restrict__ out)
{
    __shared__ __align__(16) u16 As[64][40];
    __shared__ __align__(16) u16 Bs[64][40];
    const int m0 = blockIdx.y * 64, n0 = blockIdx.x * 64;
    const int tid = threadIdx.x;
    const int wave = tid >> 6, lane = tid & 63;
    const int lrow = lane & 15, lquad = lane >> 4;
    const int srow = tid >> 2, schunk = (tid & 3) * 8;

    floatx4 acc[4];
#pragma unroll
    for (int i = 0; i < 4; i++) acc[i] = (floatx4){0.f, 0.f, 0.f, 0.f};

    for (int k0 = 0; k0 < 1024; k0 += 32) {
        *(short8*)&As[srow][schunk] = *(const short8*)&X[(size_t)(m0 + srow) * 1024 + k0 + schunk];
        *(short8*)&Bs[srow][schunk] = *(const short8*)&WT[(size_t)(n0 + srow) * 1024 + k0 + schunk];
        __syncthreads();
        short8 a = *(const short8*)&As[wave * 16 + lrow][lquad * 8];
#pragma unroll
        for (int nt = 0; nt < 4; nt++) {
            short8 b = *(const short8*)&Bs[nt * 16 + lrow][lquad * 8];
            acc[nt] = MFMA(a, b, acc[nt]);
        }
        __syncthreads();
    }

#pragma unroll
    for (int nt = 0; nt < 4; nt++)
#pragma unroll
        for (int i = 0; i < 4; i++) {
            const int gm = m0 + wave * 16 + lquad * 4 + i;
            const int gn = n0 + nt * 16 + lrow;
            out[(size_t)gm * 1024 + gn] = acc[nt][i] + bias[gn];
        }
}

// ---------------------------------------------------------------------------
extern "C" void kernel_launch(void* const* d_in, const int* in_sizes, int n_in,
                              void* d_out, int out_size, void* d_ws, size_t ws_size,
                              hipStream_t stream) {
    u16* ws = (u16*)d_ws + 64;

    const size_t MB1 = 1024 * 1024;
    u16* WT   = ws;              // 4 transposed weights (bf16)
    u16* Qw   = ws + 4 * MB1;    // [bh][2048][64]
    u16* Kw   = ws + 8 * MB1;    // [bh][2048][64]
    u16* VTw  = ws + 12 * MB1;   // [bh][64][2048]
    u16* ctxw = ws + 16 * MB1;   // [4096][1024]
    u16* Xbf  = ws + 20 * MB1;   // x as bf16 [4096][1024]

    convert_x_kernel<<<2048, 256, 0, stream>>>((const float*)d_in[0], Xbf);
    transpose_w_kernel<<<dim3(32, 32, 4), dim3(32, 8), 0, stream>>>(
        (const float*)d_in[1], (const float*)d_in[2], (const float*)d_in[3],
        (const float*)d_in[4], WT);
    gemm_qkv_kernel<<<dim3(16, 64, 3), 256, 0, stream>>>(Xbf, WT, Qw, Kw, VTw);
    attn_kernel<<<1024, 256, 0, stream>>>(Qw, Kw, VTw, ctxw);
    gemm_out_kernel<<<dim3(16, 64), 256, 0, stream>>>(ctxw, WT + 3 * MB1, (const float*)d_in[5], (float*)d_out);
}

// Round 7
// 181.584 us; speedup vs baseline: 2.6631x; 1.1904x over previous
//
#include <hip/hip_runtime.h>
#include <stdint.h>

typedef unsigned short u16;
typedef __attribute__((ext_vector_type(8))) short short8;
typedef __attribute__((ext_vector_type(4))) float floatx4;
typedef __attribute__((ext_vector_type(4))) u16 ushort4v;

typedef __attribute__((address_space(1))) const uint32_t gu32;
typedef __attribute__((address_space(3))) uint32_t lu32;

#define MFMA(a, b, c) __builtin_amdgcn_mfma_f32_16x16x32_bf16((a), (b), (c), 0, 0, 0)

__device__ __forceinline__ u16 f2bf(float f) {
    union { float f; uint32_t u; } x; x.f = f;
    uint32_t u = x.u;
    u += 0x7fffu + ((u >> 16) & 1u);
    return (u16)(u >> 16);
}

// async global->LDS DMA, 16B per lane; lds base must be wave-uniform,
// HW scatters to base + lane*16 (m104/m108).
__device__ __forceinline__ void async16(u16* lds, const u16* g) {
    __builtin_amdgcn_global_load_lds((gu32*)g, (lu32*)lds, 16, 0, 0);
}

// ---------------------------------------------------------------------------
// prep: z=0..3 transpose W_z [k][n] fp32 -> WT [n][k] bf16; z=4 convert x.
// ---------------------------------------------------------------------------
__global__ __launch_bounds__(256) void prep_kernel(
    const float* __restrict__ x,
    const float* __restrict__ W0, const float* __restrict__ W1,
    const float* __restrict__ W2, const float* __restrict__ W3,
    u16* __restrict__ WT, u16* __restrict__ Xbf)
{
    const int z = blockIdx.z;
    const int tx = threadIdx.x, ty = threadIdx.y;
    if (z == 4) {
        const int bid = blockIdx.y * 32 + blockIdx.x;
        const int t = ty * 32 + tx;
        const size_t base = ((size_t)bid * 256 + t) * 16;
        const float* xf = x + base;
        short8 v0, v1;
#pragma unroll
        for (int j = 0; j < 8; j++) v0[j] = (short)f2bf(xf[j]);
#pragma unroll
        for (int j = 0; j < 8; j++) v1[j] = (short)f2bf(xf[8 + j]);
        *(short8*)&Xbf[base] = v0;
        *(short8*)&Xbf[base + 8] = v1;
        return;
    }
    __shared__ u16 tile[32][33];
    const float* W = (z == 0) ? W0 : (z == 1) ? W1 : (z == 2) ? W2 : W3;
    u16* dst = WT + (size_t)z * 1024 * 1024;
    const int n0 = blockIdx.x * 32, k0 = blockIdx.y * 32;
#pragma unroll
    for (int i = 0; i < 4; i++)
        tile[ty + i * 8][tx] = f2bf(W[(size_t)(k0 + ty + i * 8) * 1024 + n0 + tx]);
    __syncthreads();
#pragma unroll
    for (int i = 0; i < 4; i++)
        dst[(size_t)(n0 + ty + i * 8) * 1024 + k0 + tx] = tile[tx][ty + i * 8];
}

// ---------------------------------------------------------------------------
// QKV GEMM, m97 structure: 128x128 tile, BK=32, global_load_lds width=16.
// 4 waves in 2x2 quadrants, 4x4 16x16x32 MFMA accs each.
// XCD swizzle: xcd=bid&7 owns m-rows [xcd*4, xcd*4+4) for all n and all mats
// -> each X row-block hits one XCD's L2 only.
// C/D mapping (m89, HW-confirmed): row=lquad*4+i, col=lrow.
// ---------------------------------------------------------------------------
__global__ __launch_bounds__(256) void gemm_qkv_kernel(
    const u16* __restrict__ X, const u16* __restrict__ WT,
    u16* __restrict__ Q, u16* __restrict__ Kout, u16* __restrict__ VT)
{
    __shared__ __align__(16) u16 As[128 * 32];
    __shared__ __align__(16) u16 Bs[128 * 32];
    const int bid = blockIdx.x;
    const int xcd = bid & 7;
    const int idx = bid >> 3;          // 0..95
    const int mat = idx >> 5;          // 0..2
    const int rr  = (idx >> 3) & 3;    // 0..3
    const int nn  = idx & 7;           // 0..7
    const int m0 = (xcd * 4 + rr) * 128;
    const int n0 = nn * 128;
    const u16* BW = WT + (size_t)mat * 1024 * 1024;
    const int tid = threadIdx.x;
    const int wave = tid >> 6, lane = tid & 63;
    const int lrow = lane & 15, lquad = lane >> 4;
    const int wr = (wave >> 1) * 64, wc = (wave & 1) * 64;

    // staging: wave w covers 16B-chunk indices [w*128, w*128+128), 2 calls/op
    const int ci0 = wave * 128 + lane;
    const int ci1 = ci0 + 64;
    const int ar0 = ci0 >> 2, ac0 = (ci0 & 3) * 8;
    const int ar1 = ci1 >> 2, ac1 = (ci1 & 3) * 8;
    u16* ldsA0 = As + (size_t)(wave * 128) * 8;      // wave-uniform bases
    u16* ldsA1 = As + (size_t)(wave * 128 + 64) * 8;
    u16* ldsB0 = Bs + (size_t)(wave * 128) * 8;
    u16* ldsB1 = Bs + (size_t)(wave * 128 + 64) * 8;
    const u16* gA0 = &X[(size_t)(m0 + ar0) * 1024 + ac0];
    const u16* gA1 = &X[(size_t)(m0 + ar1) * 1024 + ac1];
    const u16* gB0 = &BW[(size_t)(n0 + ar0) * 1024 + ac0];
    const u16* gB1 = &BW[(size_t)(n0 + ar1) * 1024 + ac1];

    floatx4 acc[4][4];
#pragma unroll
    for (int mt = 0; mt < 4; mt++)
#pragma unroll
        for (int nt = 0; nt < 4; nt++) acc[mt][nt] = (floatx4){0.f, 0.f, 0.f, 0.f};

    for (int k0 = 0; k0 < 1024; k0 += 32) {
        __syncthreads();              // prior tile's ds_reads done
        async16(ldsA0, gA0 + k0);
        async16(ldsA1, gA1 + k0);
        async16(ldsB0, gB0 + k0);
        async16(ldsB1, gB1 + k0);
        __syncthreads();              // barrier drains vmcnt -> tile visible
        short8 af[4], bf[4];
#pragma unroll
        for (int mt = 0; mt < 4; mt++)
            af[mt] = *(const short8*)&As[(wr + mt * 16 + lrow) * 32 + lquad * 8];
#pragma unroll
        for (int nt = 0; nt < 4; nt++)
            bf[nt] = *(const short8*)&Bs[(wc + nt * 16 + lrow) * 32 + lquad * 8];
#pragma unroll
        for (int mt = 0; mt < 4; mt++)
#pragma unroll
            for (int nt = 0; nt < 4; nt++)
                acc[mt][nt] = MFMA(af[mt], bf[nt], acc[mt][nt]);
    }

#pragma unroll
    for (int mt = 0; mt < 4; mt++) {
        const int gm = m0 + wr + mt * 16 + lquad * 4;
        const int b_ = gm >> 11;
        const int s  = gm & 2047;
#pragma unroll
        for (int nt = 0; nt < 4; nt++) {
            const int gn = n0 + wc + nt * 16 + lrow;
            const int h = gn >> 6, hd = gn & 63;
            const int bh = b_ * 16 + h;
            if (mat == 2) {
                ushort4v v;
#pragma unroll
                for (int i = 0; i < 4; i++) v[i] = f2bf(acc[mt][nt][i]);
                *(ushort4v*)&VT[((size_t)bh * 64 + hd) * 2048 + s] = v;
            } else {
                u16* dst = (mat == 0) ? Q : Kout;
#pragma unroll
                for (int i = 0; i < 4; i++)
                    dst[((size_t)bh * 2048 + s + i) * 64 + hd] = f2bf(acc[mt][nt][i]);
            }
        }
    }
}

// ---------------------------------------------------------------------------
// Flash attention (causal), LDS-shared K/V tiles (r6 kernel, unchanged).
// ---------------------------------------------------------------------------
__global__ __launch_bounds__(256, 4) void attn_kernel(
    const u16* __restrict__ Q, const u16* __restrict__ Kk,
    const u16* __restrict__ VT, u16* __restrict__ ctx)
{
    __shared__ __align__(16) u16 Ks[64][72];
    __shared__ __align__(16) u16 Vs[64][72];
    __shared__ __align__(16) u16 P[4][16][72];
    const int tid = threadIdx.x, wave = tid >> 6, lane = tid & 63;
    const int lrow = lane & 15, lquad = lane >> 4;
    const float scale = 0.125f;
    const float NEGINF = -__builtin_inff();

    const int bh = blockIdx.x & 31;
    const int g = blockIdx.x >> 5;
    const int qb = (g < 16) ? (31 - g) : (g - 16);
    const int ntiles = qb + 1;
    const int q0 = qb * 64 + wave * 16;

    const u16* Qb = Q  + (size_t)bh * 2048 * 64;
    const u16* Kb = Kk + (size_t)bh * 2048 * 64;
    const u16* Vb = VT + (size_t)bh * 64 * 2048;

    const short8 qf0 = *(const short8*)&Qb[(size_t)(q0 + lrow) * 64 + lquad * 8];
    const short8 qf1 = *(const short8*)&Qb[(size_t)(q0 + lrow) * 64 + 32 + lquad * 8];

    const int myq = q0 + lrow;
    float m_s = NEGINF, l_s = 0.f;
    floatx4 o[4];
#pragma unroll
    for (int i = 0; i < 4; i++) o[i] = (floatx4){0.f, 0.f, 0.f, 0.f};

    const int r0 = tid >> 3, c0 = (tid & 7) * 8;
    const int r1 = (tid + 256) >> 3, c1 = c0;

    short8 kreg0 = *(const short8*)&Kb[(size_t)r0 * 64 + c0];
    short8 kreg1 = *(const short8*)&Kb[(size_t)r1 * 64 + c1];
    short8 vreg0 = *(const short8*)&Vb[(size_t)r0 * 2048 + c0];
    short8 vreg1 = *(const short8*)&Vb[(size_t)r1 * 2048 + c1];

    for (int kt = 0; kt < ntiles; kt++) {
        __syncthreads();
        *(short8*)&Ks[r0][c0] = kreg0;
        *(short8*)&Ks[r1][c1] = kreg1;
        *(short8*)&Vs[r0][c0] = vreg0;
        *(short8*)&Vs[r1][c1] = vreg1;
        if (kt + 1 < ntiles) {
            kreg0 = *(const short8*)&Kb[(size_t)((kt + 1) * 64 + r0) * 64 + c0];
            kreg1 = *(const short8*)&Kb[(size_t)((kt + 1) * 64 + r1) * 64 + c1];
            vreg0 = *(const short8*)&Vb[(size_t)r0 * 2048 + (kt + 1) * 64 + c0];
            vreg1 = *(const short8*)&Vb[(size_t)r1 * 2048 + (kt + 1) * 64 + c1];
        }
        __syncthreads();

        floatx4 s[4];
#pragma unroll
        for (int nt = 0; nt < 4; nt++) {
            const short8 kf0 = *(const short8*)&Ks[nt * 16 + lrow][lquad * 8];
            const short8 kf1 = *(const short8*)&Ks[nt * 16 + lrow][32 + lquad * 8];
            floatx4 a = (floatx4){0.f, 0.f, 0.f, 0.f};
            a = MFMA(kf0, qf0, a);
            a = MFMA(kf1, qf1, a);
            s[nt] = a;
        }

        const bool diag = (kt == ntiles - 1);
        float mx = NEGINF;
#pragma unroll
        for (int nt = 0; nt < 4; nt++)
#pragma unroll
            for (int i = 0; i < 4; i++) {
                float v = s[nt][i] * scale;
                if (diag && (kt * 64 + nt * 16 + lquad * 4 + i > myq)) v = NEGINF;
                s[nt][i] = v;
                mx = fmaxf(mx, v);
            }
        mx = fmaxf(mx, __shfl_xor(mx, 16));
        mx = fmaxf(mx, __shfl_xor(mx, 32));
        const float mnew = fmaxf(m_s, mx);
        const float alpha = __expf(m_s - mnew);
        m_s = mnew;
        float sum = 0.f;
#pragma unroll
        for (int nt = 0; nt < 4; nt++)
#pragma unroll
            for (int i = 0; i < 4; i++) {
                const float pv = __expf(s[nt][i] - mnew);
                s[nt][i] = pv;
                sum += pv;
            }
        sum += __shfl_xor(sum, 16);
        sum += __shfl_xor(sum, 32);
        l_s = l_s * alpha + sum;
#pragma unroll
        for (int ht = 0; ht < 4; ht++)
#pragma unroll
            for (int i = 0; i < 4; i++) o[ht][i] *= alpha;

#pragma unroll
        for (int nt = 0; nt < 4; nt++) {
            uint32_t pk0 = (uint32_t)f2bf(s[nt][0]) | ((uint32_t)f2bf(s[nt][1]) << 16);
            uint32_t pk1 = (uint32_t)f2bf(s[nt][2]) | ((uint32_t)f2bf(s[nt][3]) << 16);
            uint2 pk = {pk0, pk1};
            *(uint2*)&P[wave][lrow][nt * 16 + lquad * 4] = pk;
        }
#pragma unroll
        for (int st = 0; st < 2; st++) {
            const short8 pf = *(const short8*)&P[wave][lrow][st * 32 + lquad * 8];
#pragma unroll
            for (int ht = 0; ht < 4; ht++) {
                const short8 vf = *(const short8*)&Vs[ht * 16 + lrow][st * 32 + lquad * 8];
                o[ht] = MFMA(vf, pf, o[ht]);
            }
        }
    }

    const int b_ = bh >> 4, h_ = bh & 15;
    const float inv_l = 1.0f / l_s;
#pragma unroll
    for (int ht = 0; ht < 4; ht++) {
        uint32_t pk0 = (uint32_t)f2bf(o[ht][0] * inv_l) | ((uint32_t)f2bf(o[ht][1] * inv_l) << 16);
        uint32_t pk1 = (uint32_t)f2bf(o[ht][2] * inv_l) | ((uint32_t)f2bf(o[ht][3] * inv_l) << 16);
        uint2 pk = {pk0, pk1};
        *(uint2*)&ctx[((size_t)(b_ * 2048 + q0 + lrow)) * 1024 + h_ * 64 + ht * 16 + lquad * 4] = pk;
    }
}

// ---------------------------------------------------------------------------
// Output projection, same m97 structure; epilogue adds bias, stores fp32.
// ---------------------------------------------------------------------------
__global__ __launch_bounds__(256) void gemm_out_kernel(
    const u16* __restrict__ X, const u16* __restrict__ WT,
    const float* __restrict__ bias, float* __restrict__ out)
{
    __shared__ __align__(16) u16 As[128 * 32];
    __shared__ __align__(16) u16 Bs[128 * 32];
    const int bid = blockIdx.x;
    const int xcd = bid & 7;
    const int idx = bid >> 3;          // 0..31
    const int rr  = idx >> 3;          // 0..3
    const int nn  = idx & 7;           // 0..7
    const int m0 = (xcd * 4 + rr) * 128;
    const int n0 = nn * 128;
    const int tid = threadIdx.x;
    const int wave = tid >> 6, lane = tid & 63;
    const int lrow = lane & 15, lquad = lane >> 4;
    const int wr = (wave >> 1) * 64, wc = (wave & 1) * 64;

    const int ci0 = wave * 128 + lane;
    const int ci1 = ci0 + 64;
    const int ar0 = ci0 >> 2, ac0 = (ci0 & 3) * 8;
    const int ar1 = ci1 >> 2, ac1 = (ci1 & 3) * 8;
    u16* ldsA0 = As + (size_t)(wave * 128) * 8;
    u16* ldsA1 = As + (size_t)(wave * 128 + 64) * 8;
    u16* ldsB0 = Bs + (size_t)(wave * 128) * 8;
    u16* ldsB1 = Bs + (size_t)(wave * 128 + 64) * 8;
    const u16* gA0 = &X[(size_t)(m0 + ar0) * 1024 + ac0];
    const u16* gA1 = &X[(size_t)(m0 + ar1) * 1024 + ac1];
    const u16* gB0 = &WT[(size_t)(n0 + ar0) * 1024 + ac0];
    const u16* gB1 = &WT[(size_t)(n0 + ar1) * 1024 + ac1];

    floatx4 acc[4][4];
#pragma unroll
    for (int mt = 0; mt < 4; mt++)
#pragma unroll
        for (int nt = 0; nt < 4; nt++) acc[mt][nt] = (floatx4){0.f, 0.f, 0.f, 0.f};

    for (int k0 = 0; k0 < 1024; k0 += 32) {
        __syncthreads();
        async16(ldsA0, gA0 + k0);
        async16(ldsA1, gA1 + k0);
        async16(ldsB0, gB0 + k0);
        async16(ldsB1, gB1 + k0);
        __syncthreads();
        short8 af[4], bf[4];
#pragma unroll
        for (int mt = 0; mt < 4; mt++)
            af[mt] = *(const short8*)&As[(wr + mt * 16 + lrow) * 32 + lquad * 8];
#pragma unroll
        for (int nt = 0; nt < 4; nt++)
            bf[nt] = *(const short8*)&Bs[(wc + nt * 16 + lrow) * 32 + lquad * 8];
#pragma unroll
        for (int mt = 0; mt < 4; mt++)
#pragma unroll
            for (int nt = 0; nt < 4; nt++)
                acc[mt][nt] = MFMA(af[mt], bf[nt], acc[mt][nt]);
    }

#pragma unroll
    for (int mt = 0; mt < 4; mt++) {
        const int gm = m0 + wr + mt * 16 + lquad * 4;
#pragma unroll
        for (int nt = 0; nt < 4; nt++) {
            const int gn = n0 + wc + nt * 16 + lrow;
            const float bv = bias[gn];
#pragma unroll
            for (int i = 0; i < 4; i++)
                out[(size_t)(gm + i) * 1024 + gn] = acc[mt][nt][i] + bv;
        }
    }
}

// ---------------------------------------------------------------------------
extern "C" void kernel_launch(void* const* d_in, const int* in_sizes, int n_in,
                              void* d_out, int out_size, void* d_ws, size_t ws_size,
                              hipStream_t stream) {
    u16* ws = (u16*)d_ws + 64;

    const size_t MB1 = 1024 * 1024;
    u16* WT   = ws;              // 4 transposed weights (bf16)
    u16* Qw   = ws + 4 * MB1;    // [bh][2048][64]
    u16* Kw   = ws + 8 * MB1;    // [bh][2048][64]
    u16* VTw  = ws + 12 * MB1;   // [bh][64][2048]
    u16* ctxw = ws + 16 * MB1;   // [4096][1024]
    u16* Xbf  = ws + 20 * MB1;   // x as bf16 [4096][1024]

    prep_kernel<<<dim3(32, 32, 5), dim3(32, 8), 0, stream>>>(
        (const float*)d_in[0], (const float*)d_in[1], (const float*)d_in[2],
        (const float*)d_in[3], (const float*)d_in[4], WT, Xbf);
    gemm_qkv_kernel<<<768, 256, 0, stream>>>(Xbf, WT, Qw, Kw, VTw);
    attn_kernel<<<1024, 256, 0, stream>>>(Qw, Kw, VTw, ctxw);
    gemm_out_kernel<<<256, 256, 0, stream>>>(ctxw, WT + 3 * MB1, (const float*)d_in[5], (float*)d_out);
}